// Round 13
// baseline (140.106 us; speedup 1.0000x reference)
//
#include <hip/hip_runtime.h>
#include <hip/hip_bf16.h>
#include <hip/hip_cooperative_groups.h>
#include <math.h>

namespace cg = cooperative_groups;

#define HF 32
#define WF 88
#define NCAM 6
#define CC 128
#define ZD 128
#define YD 8
#define XD 128

using f32x4  = __attribute__((ext_vector_type(4))) float;
using bf16x8 = __attribute__((ext_vector_type(8))) short;
using h2     = __attribute__((ext_vector_type(2))) _Float16;

#if defined(__has_builtin)
#if __has_builtin(__builtin_amdgcn_fdot2)
#define HAVE_FDOT2 1
#endif
#endif
__device__ __forceinline__ float fdot2f(h2 a, h2 b, float c) {
#ifdef HAVE_FDOT2
  return __builtin_amdgcn_fdot2(a, b, c, false);
#else
  return c + (float)a[0] * (float)b[0] + (float)a[1] * (float)b[1];
#endif
}

// ---- workspace layout (bytes) ----
#define OFF_P    0ull
#define OFF_W    512ull                        // Wp: 9*131072*2 = 2359296
#define OFF_CAMT (OFF_W + 2359296ull)          // camT2(fp16 pairs): 8552448 of 8650752 slot (reused as conv1 after k2)
#define OFF_F    (OFF_CAMT + 8650752ull)       // Fpack: 130*130*1024*2 = 34611200
#define OFF_CONV (OFF_F + 34611200ull)         // conv partial 0: 128*16384*4 = 8388608

// ============ K_pre: fused mats + transpose(->fp16 x-pairs) + packw (FROZEN) ====
__global__ __launch_bounds__(256) void k_pre(const float* __restrict__ feat,
                                             const float* __restrict__ conv_w,
                                             const float* __restrict__ cam2ego,
                                             const float* __restrict__ intr,
                                             unsigned* __restrict__ camT2,
                                             __hip_bfloat16* __restrict__ wp,
                                             float* __restrict__ P) {
  __shared__ float tile[128 * 89];
  const int b = blockIdx.x;
  const int t = threadIdx.x;
  if (b < 192) {
    const int s = b >> 5;
    const int hrow = b & 31;
    for (int idx = t; idx < 128 * 88; idx += 256) {
      const int c = idx / 88;
      const int w = idx - c * 88;
      tile[c * 89 + w] = feat[((size_t)(s * CC + c) * HF + hrow) * WF + w];
    }
    __syncthreads();
    unsigned* dst = camT2 + (size_t)(s * 32 + hrow) * 87 * 128;
    for (int idx = t; idx < 87 * 128; idx += 256) {
      const int px = idx >> 7;
      const int c = idx & 127;
      union { _Float16 h[2]; unsigned u; } pr;
      pr.h[0] = (_Float16)tile[c * 89 + px];
      pr.h[1] = (_Float16)tile[c * 89 + px + 1];
      dst[px * 128 + c] = pr.u;
    }
  } else if (b < 704) {
    const int tt = (b - 192) * 256 + t;
    float v[9];
    #pragma unroll
    for (int d = 0; d < 9; d++) v[d] = conv_w[(size_t)tt * 9 + d];
    #pragma unroll
    for (int d = 0; d < 9; d++) wp[(size_t)d * 131072 + tt] = __float2bfloat16(v[d]);
  } else {
    const int s = t;
    if (s >= NCAM) return;
    const float* M0 = cam2ego;
    const float* Ms = cam2ego + s * 16;
    float Rb[9], tb[3];
    for (int i = 0; i < 3; i++)
      for (int j = 0; j < 3; j++) {
        float v = 0.f;
        for (int k = 0; k < 3; k++) v += Ms[k * 4 + i] * M0[k * 4 + j];
        Rb[i * 3 + j] = v;
      }
    for (int i = 0; i < 3; i++) {
      float v = 0.f;
      for (int k = 0; k < 3; k++) v += Ms[k * 4 + i] * (M0[k * 4 + 3] - Ms[k * 4 + 3]);
      tb[i] = v;
    }
    const float* Ks = intr + s * 16;
    const float sx = (float)WF / 704.0f * 0.44f;
    const float sy = (float)HF / 256.0f * 0.284f;
    const float fx = Ks[0] * sx, fy = Ks[5] * sy;
    const float cx = Ks[2] * sx, cy = Ks[6] * sy;
    float* p = P + s * 12;
    for (int j = 0; j < 3; j++) p[j]     = fx * Rb[j]     + cx * Rb[6 + j];
    p[3]  = fx * tb[0] + cx * tb[2];
    for (int j = 0; j < 3; j++) p[4 + j] = fy * Rb[3 + j] + cy * Rb[6 + j];
    p[7]  = fy * tb[1] + cy * tb[2];
    for (int j = 0; j < 3; j++) p[8 + j] = Rb[6 + j];
    p[11] = tb[2];
  }
}

// ============ K2: project + bilinear + mask-average -> Fpack (halo-padded) ====
// v8 (REVERTED to best measured, round 11): one cell per WAVE, no LDS, no
// barriers, wave-uniform ctz loop, __shfl rec broadcast, 2x16B stores.
__global__ __launch_bounds__(256) void k2_sample(const unsigned* __restrict__ camT2,
                                                 const float* __restrict__ P,
                                                 __hip_bfloat16* __restrict__ F) {
  const int wv = threadIdx.x >> 6;
  const int l  = threadIdx.x & 63;
  const int cell = blockIdx.x * 4 + wv;       // 0..16899
  const int bz = cell / 130;
  const int bx = cell - bz * 130;
  const int zi = bz - 1, xi = bx - 1;
  __hip_bfloat16* Fb = F + (size_t)cell * 1024;

  if (zi < 0 || zi >= ZD || xi < 0 || xi >= XD) {   // wave-uniform
    const uint4 z4 = {0u, 0u, 0u, 0u};
    *reinterpret_cast<uint4*>(Fb + (2 * l) * 8)     = z4;
    *reinterpret_cast<uint4*>(Fb + (2 * l + 1) * 8) = z4;
    return;
  }

  int offA = 0, offB = 0;
  unsigned pwA = 0, pwB = 0;
  bool vflag = false;
  if (l < 48) {
    const int y = l / 6, s = l - y * 6;
    const float* pp = P + s * 12;
    const float vx = 100.0f / 128.0f;
    const float xw = xi * vx - 50.0f + vx * 0.5f;
    const float zw = zi * vx - 50.0f + vx * 0.5f;
    const float yw = y * 1.25f - 4.0f + 0.625f;
    const float zc = pp[8] * xw + pp[9] * yw + pp[10] * zw + pp[11];
    const float xp = pp[0] * xw + pp[1] * yw + pp[2] * zw + pp[3];
    const float yp = pp[4] * xw + pp[5] * yw + pp[6] * zw + pp[7];
    const float dep = fmaxf(zc, 1e-4f);
    const float pxf = xp / dep, pyf = yp / dep;
    const bool valid = (pxf > -0.5f && pxf < (float)WF - 0.5f &&
                        pyf > -0.5f && pyf < (float)HF - 0.5f && zc > 0.0f);
    const float px = pxf * ((float)WF / (float)(WF - 1)) - 0.5f;
    const float py = pyf * ((float)HF / (float)(HF - 1)) - 0.5f;
    const float fx0 = floorf(px), fy0 = floorf(py);
    const float ddx = px - fx0, ddy = py - fy0;
    const int x0i = (int)fx0, y0i = (int)fy0;
    const float vf = valid ? 1.0f : 0.0f;
    const float wxl = (1.0f - ddx) * vf, wxr = ddx * vf;
    int pxi; float sl, sr;
    if (x0i >= 0 && x0i <= 86)      { pxi = x0i; sl = wxl; sr = wxr; }
    else if (x0i == -1)             { pxi = 0;   sl = wxr; sr = 0.f; }
    else if (x0i == 87)             { pxi = 86;  sl = 0.f; sr = wxl; }
    else                            { pxi = 0;   sl = 0.f; sr = 0.f; }
    const float fA = ((unsigned)y0i < (unsigned)HF) ? (1.0f - ddy) : 0.0f;
    const float fB = ((unsigned)(y0i + 1) < (unsigned)HF) ? ddy : 0.0f;
    const int rowA = min(max(y0i, 0), HF - 1);
    const int rowB = min(max(y0i + 1, 0), HF - 1);
    offA = ((s * HF + rowA) * 87 + pxi) * 128;
    offB = ((s * HF + rowB) * 87 + pxi) * 128;
    union { _Float16 h[2]; unsigned u; } wa, wb;
    wa.h[0] = (_Float16)(sl * fA); wa.h[1] = (_Float16)(sr * fA);
    wb.h[0] = (_Float16)(sl * fB); wb.h[1] = (_Float16)(sr * fB);
    pwA = wa.u; pwB = wb.u;
    vflag = ((sl + sr) * (fA + fB)) > 0.0f;
  }
  const unsigned long long m = __ballot(vflag);   // per-wave, uniform

  float accA[8], accB[8];
  #pragma unroll
  for (int y = 0; y < 8; y++) { accA[y] = 0.f; accB[y] = 0.f; }

  #pragma unroll
  for (int y = 0; y < 8; y++) {
    unsigned ms = (unsigned)((m >> (6 * y)) & 63ull);   // wave-uniform
    const int c = __popc(ms);
    while (ms) {
      const int s = __builtin_ctz(ms);
      ms &= ms - 1;
      const int src = y * 6 + s;                        // uniform source lane
      const int oA = __shfl(offA, src);
      const int oB = __shfl(offB, src);
      const unsigned uwA = (unsigned)__shfl((int)pwA, src);
      const unsigned uwB = (unsigned)__shfl((int)pwB, src);
      const uint2 av = *reinterpret_cast<const uint2*>(camT2 + oA + 2 * l);
      const uint2 bv = *reinterpret_cast<const uint2*>(camT2 + oB + 2 * l);
      const h2 wa = __builtin_bit_cast(h2, uwA);
      const h2 wb = __builtin_bit_cast(h2, uwB);
      accA[y] = fdot2f(__builtin_bit_cast(h2, av.x), wa, accA[y]);
      accB[y] = fdot2f(__builtin_bit_cast(h2, av.y), wa, accB[y]);
      accA[y] = fdot2f(__builtin_bit_cast(h2, bv.x), wb, accA[y]);
      accB[y] = fdot2f(__builtin_bit_cast(h2, bv.y), wb, accB[y]);
    }
    const float inv = 1.0f / (1e-6f + (float)c);
    accA[y] *= inv;
    accB[y] *= inv;
  }

  union { __hip_bfloat16 h[8]; uint4 u; } pA, pB;
  #pragma unroll
  for (int y = 0; y < 8; y++) {
    pA.h[y] = __float2bfloat16(accA[y]);
    pB.h[y] = __float2bfloat16(accB[y]);
  }
  *reinterpret_cast<uint4*>(Fb + (2 * l) * 8)     = pA.u;
  *reinterpret_cast<uint4*>(Fb + (2 * l + 1) * 8) = pB.u;
}

// ============ K_fused34: k3 (FROZEN v7 body) + grid.sync + k4 LN/GELU ============
// Cooperative: grid 256 x 512 = exactly 1 block/CU (128KB LDS). Removes the
// k3->k4 kernel boundary; grid.sync provides device-scope visibility of the
// conv partials (G16).
__device__ __forceinline__ void load_lds16(const void* g, void* l) {
  __builtin_amdgcn_global_load_lds(
      (const __attribute__((address_space(1))) unsigned int*)g,
      (__attribute__((address_space(3))) unsigned int*)l, 16, 0, 0);
}

__device__ __forceinline__ float gelu_exact(float x) {
  return 0.5f * x * (1.0f + erff(x * 0.70710678118654752440f));
}

#define K3_NT 72   // 9 taps * 8 ci-chunks (ci-half of 512, BK=64)

__global__ __launch_bounds__(512) void k_fused34(const __hip_bfloat16* __restrict__ F,
                                                 const __hip_bfloat16* __restrict__ Wp,
                                                 float* __restrict__ out0,
                                                 float* __restrict__ out1,
                                                 float* __restrict__ outp) {
  __shared__ __hip_bfloat16 lds[4][16384];  // ring: A[128][64] + B[128][64] per stage (32KB)
  const int tid = threadIdx.x;

  // ================= phase A: k3 v7 (verbatim) =================
  {
    const int orig = (blockIdx.x & 7) * 32 + (blockIdx.x >> 3);
    const int z = orig & 127;
    const int h = orig >> 7;          // ci-half
    const int ciH = h << 9;
    const int w = tid >> 6;           // wave 0..7
    const int l = tid & 63;
    const int kk = w >> 2;            // in-block K-group (ci sub-chunks)
    const int wq = w & 3;
    const int wm = wq >> 1;           // 0..1  (64 x-rows)
    const int wn = wq & 1;            // 0..1  (64 co)

    f32x4 acc[4][4];
    #pragma unroll
    for (int m = 0; m < 4; m++)
      #pragma unroll
      for (int n = 0; n < 4; n++)
        acc[m][n] = (f32x4){0.f, 0.f, 0.f, 0.f};

    auto stage_A = [&](int kt) {
      const int buf = kt & 3;
      const int d = kt >> 3;
      const int dz = d / 3, dx = d - dz * 3;
      const int ci0 = ciH + ((kt & 7) << 6);
      const int zbase = (z + dz) * 130 + dx;
      #pragma unroll
      for (int i = 0; i < 2; i++) {
        const int n = w * 128 + i * 64 + l;
        const int row = n >> 3;
        const int q = (n & 7) ^ (row & 7);
        const __hip_bfloat16* src = F + ((size_t)(zbase + row) << 10) + ci0 + (q << 3);
        load_lds16(src, &lds[buf][(w * 128 + i * 64) * 8]);
      }
    };
    auto stage_B = [&](int kt) {
      const int buf = kt & 3;
      const int d = kt >> 3;
      const int ci0 = ciH + ((kt & 7) << 6);
      #pragma unroll
      for (int i = 0; i < 2; i++) {
        const int n = w * 128 + i * 64 + l;
        const int co = n >> 3;
        const int q = (n & 7) ^ (co & 7);
        const __hip_bfloat16* src = Wp + ((size_t)d << 17) + ((size_t)co << 10) + ci0 + (q << 3);
        load_lds16(src, &lds[buf][8192 + (w * 128 + i * 64) * 8]);
      }
    };

    const int r16 = l & 15;
    const int hi = l >> 4;
    const int cslot = kk * 4 + hi;

    auto step = [&](int t, bool doStage, int wcode) {
      const int buf = t & 3;
      bf16x8 a[4], b[4];
      #pragma unroll
      for (int m = 0; m < 4; m++) {
        const int r = wm * 64 + m * 16 + r16;
        const int slot = cslot ^ (r & 7);
        a[m] = *reinterpret_cast<const bf16x8*>(&lds[buf][r * 64 + slot * 8]);
      }
      #pragma unroll
      for (int n = 0; n < 2; n++) {
        const int co = wn * 64 + n * 16 + r16;
        const int slot = cslot ^ (co & 7);
        b[n] = *reinterpret_cast<const bf16x8*>(&lds[buf][8192 + co * 64 + slot * 8]);
      }
      if (doStage) stage_A(t + 3);
      __builtin_amdgcn_s_barrier();
      __builtin_amdgcn_s_setprio(1);
      #pragma unroll
      for (int m = 0; m < 4; m++) {
        acc[m][0] = __builtin_amdgcn_mfma_f32_16x16x32_bf16(a[m], b[0], acc[m][0], 0, 0, 0);
        acc[m][1] = __builtin_amdgcn_mfma_f32_16x16x32_bf16(a[m], b[1], acc[m][1], 0, 0, 0);
      }
      __builtin_amdgcn_s_setprio(0);
      __builtin_amdgcn_s_barrier();
      #pragma unroll
      for (int n = 2; n < 4; n++) {
        const int co = wn * 64 + n * 16 + r16;
        const int slot = cslot ^ (co & 7);
        b[n] = *reinterpret_cast<const bf16x8*>(&lds[buf][8192 + co * 64 + slot * 8]);
      }
      if (doStage) stage_B(t + 3);
      __builtin_amdgcn_s_barrier();
      __builtin_amdgcn_s_setprio(1);
      #pragma unroll
      for (int m = 0; m < 4; m++) {
        acc[m][2] = __builtin_amdgcn_mfma_f32_16x16x32_bf16(a[m], b[2], acc[m][2], 0, 0, 0);
        acc[m][3] = __builtin_amdgcn_mfma_f32_16x16x32_bf16(a[m], b[3], acc[m][3], 0, 0, 0);
      }
      __builtin_amdgcn_s_setprio(0);
      if (wcode == 8)      asm volatile("s_waitcnt vmcnt(8)" ::: "memory");
      else if (wcode == 4) asm volatile("s_waitcnt vmcnt(4)" ::: "memory");
      else if (wcode == 0) asm volatile("s_waitcnt vmcnt(0)" ::: "memory");
      __builtin_amdgcn_s_barrier();
    };

    stage_A(0); stage_B(0); stage_A(1); stage_B(1); stage_A(2); stage_B(2);
    asm volatile("s_waitcnt vmcnt(8)" ::: "memory");
    __builtin_amdgcn_s_barrier();

    for (int t = 0; t < K3_NT - 3; ++t) step(t, true, 8);
    step(K3_NT - 3, false, 4);
    step(K3_NT - 2, false, 0);
    step(K3_NT - 1, false, -1);

    float* red = reinterpret_cast<float*>(&lds[0][0]);
    if (kk == 1) {
      float* dst = red + wq * 4096;
      #pragma unroll
      for (int m = 0; m < 4; m++)
        #pragma unroll
        for (int n = 0; n < 4; n++)
          *reinterpret_cast<f32x4*>(&dst[(m * 4 + n) * 256 + l * 4]) = acc[m][n];
    }
    __syncthreads();
    if (kk == 0) {
      const float* srcr = red + wq * 4096;
      float* outP = h ? out1 : out0;
      #pragma unroll
      for (int m = 0; m < 4; m++) {
        const int xr = wm * 64 + m * 16 + hi * 4;
        #pragma unroll
        for (int n = 0; n < 4; n++) {
          f32x4 o = *reinterpret_cast<const f32x4*>(&srcr[(m * 4 + n) * 256 + l * 4]);
          f32x4 r = acc[m][n] + o;
          const int co = wn * 64 + n * 16 + r16;
          *reinterpret_cast<f32x4*>(&outP[((size_t)co << 14) + (z << 7) + xr]) = r;
        }
      }
    }
  }

  // ================= grid-wide sync: partials visible device-wide =================
  cg::this_grid().sync();

  // ================= phase B: k4 LN + exact GELU (blocks 0..127) =================
  if (blockIdx.x < 128) {
    const int co = blockIdx.x;
    const int t = tid;                       // 0..511
    const float4* p0 = reinterpret_cast<const float4*>(out0 + ((size_t)co << 14));
    const float4* p1 = reinterpret_cast<const float4*>(out1 + ((size_t)co << 14));
    float4 v[8];
    float s = 0.f, s2 = 0.f;
    #pragma unroll
    for (int i = 0; i < 8; i++) {
      float4 a = p0[t + (i << 9)];
      float4 b = p1[t + (i << 9)];
      float4 r;
      r.x = a.x + b.x; r.y = a.y + b.y; r.z = a.z + b.z; r.w = a.w + b.w;
      v[i] = r;
      s  += r.x + r.y + r.z + r.w;
      s2 += r.x * r.x + r.y * r.y + r.z * r.z + r.w * r.w;
    }
    #pragma unroll
    for (int off = 32; off > 0; off >>= 1) {
      s  += __shfl_down(s, off);
      s2 += __shfl_down(s2, off);
    }
    float* redf = reinterpret_cast<float*>(&lds[0][0]);  // reuse LDS (post-sync)
    const int wv2 = t >> 6, ln2 = t & 63;
    if (ln2 == 0) { redf[wv2] = s; redf[wv2 + 8] = s2; }
    __syncthreads();
    if (t == 0) {
      float S = 0.f, S2 = 0.f;
      #pragma unroll
      for (int i = 0; i < 8; i++) { S += redf[i]; S2 += redf[i + 8]; }
      float mu = S * (1.0f / 16384.0f);
      float var = S2 * (1.0f / 16384.0f) - mu * mu;
      redf[16] = mu;
      redf[17] = 1.0f / sqrtf(var + 1e-5f);
    }
    __syncthreads();
    const float mu = redf[16], inv = redf[17];
    float4* op = reinterpret_cast<float4*>(outp + ((size_t)co << 14));
    #pragma unroll
    for (int i = 0; i < 8; i++) {
      float4 x = v[i];
      float4 r;
      r.x = gelu_exact((x.x - mu) * inv);
      r.y = gelu_exact((x.y - mu) * inv);
      r.z = gelu_exact((x.z - mu) * inv);
      r.w = gelu_exact((x.w - mu) * inv);
      op[t + (i << 9)] = r;
    }
  }
}

extern "C" void kernel_launch(void* const* d_in, const int* in_sizes, int n_in,
                              void* d_out, int out_size, void* d_ws, size_t ws_size,
                              hipStream_t stream) {
  const float* cam_feat = (const float*)d_in[0];
  const float* cam2ego  = (const float*)d_in[1];
  const float* intr     = (const float*)d_in[2];
  const float* conv_w   = (const float*)d_in[3];
  float* out = (float*)d_out;
  char* ws = (char*)d_ws;

  float*          P     = (float*)(ws + OFF_P);
  __hip_bfloat16* Wp    = (__hip_bfloat16*)(ws + OFF_W);
  unsigned*       camT2 = (unsigned*)(ws + OFF_CAMT);
  __hip_bfloat16* F     = (__hip_bfloat16*)(ws + OFF_F);
  float*          conv0 = (float*)(ws + OFF_CONV);
  float*          conv1 = (float*)(ws + OFF_CAMT);  // camT2 slot is dead after k2

  hipLaunchKernelGGL(k_pre, dim3(705), dim3(256), 0, stream,
                     cam_feat, conv_w, cam2ego, intr, camT2, Wp, P);
  hipLaunchKernelGGL(k2_sample, dim3(4225), dim3(256), 0, stream, camT2, P, F);

  const __hip_bfloat16* Fc  = F;
  const __hip_bfloat16* Wpc = Wp;
  float* c0 = conv0;
  float* c1 = conv1;
  float* op = out;
  void* kargs[] = {(void*)&Fc, (void*)&Wpc, (void*)&c0, (void*)&c1, (void*)&op};
  hipLaunchCooperativeKernel((void (*)(const __hip_bfloat16*, const __hip_bfloat16*,
                                       float*, float*, float*))k_fused34,
                             dim3(256), dim3(512), kargs, 0, stream);
}

// Round 14
// 95.658 us; speedup vs baseline: 1.4646x; 1.4646x over previous
//
#include <hip/hip_runtime.h>
#include <hip/hip_bf16.h>
#include <math.h>

#define HF 32
#define WF 88
#define NCAM 6
#define CC 128
#define ZD 128
#define YD 8
#define XD 128

using f32x4  = __attribute__((ext_vector_type(4))) float;
using bf16x8 = __attribute__((ext_vector_type(8))) short;
using h2     = __attribute__((ext_vector_type(2))) _Float16;

#if defined(__has_builtin)
#if __has_builtin(__builtin_amdgcn_fdot2)
#define HAVE_FDOT2 1
#endif
#endif
__device__ __forceinline__ float fdot2f(h2 a, h2 b, float c) {
#ifdef HAVE_FDOT2
  return __builtin_amdgcn_fdot2(a, b, c, false);
#else
  return c + (float)a[0] * (float)b[0] + (float)a[1] * (float)b[1];
#endif
}

// ---- workspace layout (bytes) ----
#define OFF_P    0ull
#define OFF_W    512ull                        // Wp: 9*131072*2 = 2359296
#define OFF_CAMT (OFF_W + 2359296ull)          // camT2(fp16 pairs): 8552448 of 8650752 slot (reused as conv1 after k2)
#define OFF_F    (OFF_CAMT + 8650752ull)       // Fpack: 130*130*1024*2 = 34611200
#define OFF_CONV (OFF_F + 34611200ull)         // conv partial 0: 128*16384*4 = 8388608

// ============ K_pre: fused mats + transpose(->fp16 x-pairs) + packw (FROZEN) ====
__global__ __launch_bounds__(256) void k_pre(const float* __restrict__ feat,
                                             const float* __restrict__ conv_w,
                                             const float* __restrict__ cam2ego,
                                             const float* __restrict__ intr,
                                             unsigned* __restrict__ camT2,
                                             __hip_bfloat16* __restrict__ wp,
                                             float* __restrict__ P) {
  __shared__ float tile[128 * 89];
  const int b = blockIdx.x;
  const int t = threadIdx.x;
  if (b < 192) {
    const int s = b >> 5;
    const int hrow = b & 31;
    for (int idx = t; idx < 128 * 88; idx += 256) {
      const int c = idx / 88;
      const int w = idx - c * 88;
      tile[c * 89 + w] = feat[((size_t)(s * CC + c) * HF + hrow) * WF + w];
    }
    __syncthreads();
    unsigned* dst = camT2 + (size_t)(s * 32 + hrow) * 87 * 128;
    for (int idx = t; idx < 87 * 128; idx += 256) {
      const int px = idx >> 7;
      const int c = idx & 127;
      union { _Float16 h[2]; unsigned u; } pr;
      pr.h[0] = (_Float16)tile[c * 89 + px];
      pr.h[1] = (_Float16)tile[c * 89 + px + 1];
      dst[px * 128 + c] = pr.u;
    }
  } else if (b < 704) {
    const int tt = (b - 192) * 256 + t;
    float v[9];
    #pragma unroll
    for (int d = 0; d < 9; d++) v[d] = conv_w[(size_t)tt * 9 + d];
    #pragma unroll
    for (int d = 0; d < 9; d++) wp[(size_t)d * 131072 + tt] = __float2bfloat16(v[d]);
  } else {
    const int s = t;
    if (s >= NCAM) return;
    const float* M0 = cam2ego;
    const float* Ms = cam2ego + s * 16;
    float Rb[9], tb[3];
    for (int i = 0; i < 3; i++)
      for (int j = 0; j < 3; j++) {
        float v = 0.f;
        for (int k = 0; k < 3; k++) v += Ms[k * 4 + i] * M0[k * 4 + j];
        Rb[i * 3 + j] = v;
      }
    for (int i = 0; i < 3; i++) {
      float v = 0.f;
      for (int k = 0; k < 3; k++) v += Ms[k * 4 + i] * (M0[k * 4 + 3] - Ms[k * 4 + 3]);
      tb[i] = v;
    }
    const float* Ks = intr + s * 16;
    const float sx = (float)WF / 704.0f * 0.44f;
    const float sy = (float)HF / 256.0f * 0.284f;
    const float fx = Ks[0] * sx, fy = Ks[5] * sy;
    const float cx = Ks[2] * sx, cy = Ks[6] * sy;
    float* p = P + s * 12;
    for (int j = 0; j < 3; j++) p[j]     = fx * Rb[j]     + cx * Rb[6 + j];
    p[3]  = fx * tb[0] + cx * tb[2];
    for (int j = 0; j < 3; j++) p[4 + j] = fy * Rb[3 + j] + cy * Rb[6 + j];
    p[7]  = fy * tb[1] + cy * tb[2];
    for (int j = 0; j < 3; j++) p[8 + j] = Rb[6 + j];
    p[11] = tb[2];
  }
}

// ============ K2: project + bilinear + mask-average -> Fpack (halo-padded) ====
// v8 (best measured): one cell per WAVE, no LDS, no barriers, wave-uniform
// ctz loop, __shfl rec broadcast, 2x16B coalesced stores.
__global__ __launch_bounds__(256) void k2_sample(const unsigned* __restrict__ camT2,
                                                 const float* __restrict__ P,
                                                 __hip_bfloat16* __restrict__ F) {
  const int wv = threadIdx.x >> 6;
  const int l  = threadIdx.x & 63;
  const int cell = blockIdx.x * 4 + wv;       // 0..16899
  const int bz = cell / 130;
  const int bx = cell - bz * 130;
  const int zi = bz - 1, xi = bx - 1;
  __hip_bfloat16* Fb = F + (size_t)cell * 1024;

  if (zi < 0 || zi >= ZD || xi < 0 || xi >= XD) {   // wave-uniform
    const uint4 z4 = {0u, 0u, 0u, 0u};
    *reinterpret_cast<uint4*>(Fb + (2 * l) * 8)     = z4;
    *reinterpret_cast<uint4*>(Fb + (2 * l + 1) * 8) = z4;
    return;
  }

  int offA = 0, offB = 0;
  unsigned pwA = 0, pwB = 0;
  bool vflag = false;
  if (l < 48) {
    const int y = l / 6, s = l - y * 6;
    const float* pp = P + s * 12;
    const float vx = 100.0f / 128.0f;
    const float xw = xi * vx - 50.0f + vx * 0.5f;
    const float zw = zi * vx - 50.0f + vx * 0.5f;
    const float yw = y * 1.25f - 4.0f + 0.625f;
    const float zc = pp[8] * xw + pp[9] * yw + pp[10] * zw + pp[11];
    const float xp = pp[0] * xw + pp[1] * yw + pp[2] * zw + pp[3];
    const float yp = pp[4] * xw + pp[5] * yw + pp[6] * zw + pp[7];
    const float dep = fmaxf(zc, 1e-4f);
    const float pxf = xp / dep, pyf = yp / dep;
    const bool valid = (pxf > -0.5f && pxf < (float)WF - 0.5f &&
                        pyf > -0.5f && pyf < (float)HF - 0.5f && zc > 0.0f);
    const float px = pxf * ((float)WF / (float)(WF - 1)) - 0.5f;
    const float py = pyf * ((float)HF / (float)(HF - 1)) - 0.5f;
    const float fx0 = floorf(px), fy0 = floorf(py);
    const float ddx = px - fx0, ddy = py - fy0;
    const int x0i = (int)fx0, y0i = (int)fy0;
    const float vf = valid ? 1.0f : 0.0f;
    const float wxl = (1.0f - ddx) * vf, wxr = ddx * vf;
    int pxi; float sl, sr;
    if (x0i >= 0 && x0i <= 86)      { pxi = x0i; sl = wxl; sr = wxr; }
    else if (x0i == -1)             { pxi = 0;   sl = wxr; sr = 0.f; }
    else if (x0i == 87)             { pxi = 86;  sl = 0.f; sr = wxl; }
    else                            { pxi = 0;   sl = 0.f; sr = 0.f; }
    const float fA = ((unsigned)y0i < (unsigned)HF) ? (1.0f - ddy) : 0.0f;
    const float fB = ((unsigned)(y0i + 1) < (unsigned)HF) ? ddy : 0.0f;
    const int rowA = min(max(y0i, 0), HF - 1);
    const int rowB = min(max(y0i + 1, 0), HF - 1);
    offA = ((s * HF + rowA) * 87 + pxi) * 128;
    offB = ((s * HF + rowB) * 87 + pxi) * 128;
    union { _Float16 h[2]; unsigned u; } wa, wb;
    wa.h[0] = (_Float16)(sl * fA); wa.h[1] = (_Float16)(sr * fA);
    wb.h[0] = (_Float16)(sl * fB); wb.h[1] = (_Float16)(sr * fB);
    pwA = wa.u; pwB = wb.u;
    vflag = ((sl + sr) * (fA + fB)) > 0.0f;
  }
  const unsigned long long m = __ballot(vflag);   // per-wave, uniform

  float accA[8], accB[8];
  #pragma unroll
  for (int y = 0; y < 8; y++) { accA[y] = 0.f; accB[y] = 0.f; }

  #pragma unroll
  for (int y = 0; y < 8; y++) {
    unsigned ms = (unsigned)((m >> (6 * y)) & 63ull);   // wave-uniform
    const int c = __popc(ms);
    while (ms) {
      const int s = __builtin_ctz(ms);
      ms &= ms - 1;
      const int src = y * 6 + s;                        // uniform source lane
      const int oA = __shfl(offA, src);
      const int oB = __shfl(offB, src);
      const unsigned uwA = (unsigned)__shfl((int)pwA, src);
      const unsigned uwB = (unsigned)__shfl((int)pwB, src);
      const uint2 av = *reinterpret_cast<const uint2*>(camT2 + oA + 2 * l);
      const uint2 bv = *reinterpret_cast<const uint2*>(camT2 + oB + 2 * l);
      const h2 wa = __builtin_bit_cast(h2, uwA);
      const h2 wb = __builtin_bit_cast(h2, uwB);
      accA[y] = fdot2f(__builtin_bit_cast(h2, av.x), wa, accA[y]);
      accB[y] = fdot2f(__builtin_bit_cast(h2, av.y), wa, accB[y]);
      accA[y] = fdot2f(__builtin_bit_cast(h2, bv.x), wb, accA[y]);
      accB[y] = fdot2f(__builtin_bit_cast(h2, bv.y), wb, accB[y]);
    }
    const float inv = 1.0f / (1e-6f + (float)c);
    accA[y] *= inv;
    accB[y] *= inv;
  }

  union { __hip_bfloat16 h[8]; uint4 u; } pA, pB;
  #pragma unroll
  for (int y = 0; y < 8; y++) {
    pA.h[y] = __float2bfloat16(accA[y]);
    pB.h[y] = __float2bfloat16(accB[y]);
  }
  *reinterpret_cast<uint4*>(Fb + (2 * l) * 8)     = pA.u;
  *reinterpret_cast<uint4*>(Fb + (2 * l + 1) * 8) = pB.u;
}

// ============ K3: implicit-GEMM 3x3 conv, bf16 MFMA (FROZEN, 53.7us) ============
// v7 = v3 data paths + fine 2-phase interleave, counted vmcnt(8), setprio.
__device__ __forceinline__ void load_lds16(const void* g, void* l) {
  __builtin_amdgcn_global_load_lds(
      (const __attribute__((address_space(1))) unsigned int*)g,
      (__attribute__((address_space(3))) unsigned int*)l, 16, 0, 0);
}

#define K3_NT 72   // 9 taps * 8 ci-chunks (ci-half of 512, BK=64)

__global__ __launch_bounds__(512) void k3_gemm(const __hip_bfloat16* __restrict__ F,
                                               const __hip_bfloat16* __restrict__ Wp,
                                               float* __restrict__ out0,
                                               float* __restrict__ out1) {
  const int orig = (blockIdx.x & 7) * 32 + (blockIdx.x >> 3);
  const int z = orig & 127;
  const int h = orig >> 7;          // ci-half: 0 -> ci 0..511, 1 -> 512..1023
  const int ciH = h << 9;
  const int tid = threadIdx.x;
  const int w = tid >> 6;           // wave 0..7
  const int l = tid & 63;
  const int kk = w >> 2;            // in-block K-group (ci sub-chunks)
  const int wq = w & 3;
  const int wm = wq >> 1;           // 0..1  (64 x-rows)
  const int wn = wq & 1;            // 0..1  (64 co)
  __shared__ __hip_bfloat16 lds[4][16384];  // ring: A[128][64] + B[128][64] per stage (32KB)

  f32x4 acc[4][4];
  #pragma unroll
  for (int m = 0; m < 4; m++)
    #pragma unroll
    for (int n = 0; n < 4; n++)
      acc[m][n] = (f32x4){0.f, 0.f, 0.f, 0.f};

  auto stage_A = [&](int kt) {
    const int buf = kt & 3;
    const int d = kt >> 3;                    // tap 0..8
    const int dz = d / 3, dx = d - dz * 3;
    const int ci0 = ciH + ((kt & 7) << 6);
    const int zbase = (z + dz) * 130 + dx;
    #pragma unroll
    for (int i = 0; i < 2; i++) {
      const int n = w * 128 + i * 64 + l;
      const int row = n >> 3;
      const int q = (n & 7) ^ (row & 7);
      const __hip_bfloat16* src = F + ((size_t)(zbase + row) << 10) + ci0 + (q << 3);
      load_lds16(src, &lds[buf][(w * 128 + i * 64) * 8]);
    }
  };
  auto stage_B = [&](int kt) {
    const int buf = kt & 3;
    const int d = kt >> 3;
    const int ci0 = ciH + ((kt & 7) << 6);
    #pragma unroll
    for (int i = 0; i < 2; i++) {
      const int n = w * 128 + i * 64 + l;
      const int co = n >> 3;
      const int q = (n & 7) ^ (co & 7);
      const __hip_bfloat16* src = Wp + ((size_t)d << 17) + ((size_t)co << 10) + ci0 + (q << 3);
      load_lds16(src, &lds[buf][8192 + (w * 128 + i * 64) * 8]);
    }
  };

  const int r16 = l & 15;
  const int hi = l >> 4;
  const int cslot = kk * 4 + hi;              // 16B ci-chunk 0..7 (kk-split)

  auto step = [&](int t, bool doStage, int wcode) {
    const int buf = t & 3;
    bf16x8 a[4], b[4];
    // ---------- phase 0 ----------
    #pragma unroll
    for (int m = 0; m < 4; m++) {
      const int r = wm * 64 + m * 16 + r16;
      const int slot = cslot ^ (r & 7);
      a[m] = *reinterpret_cast<const bf16x8*>(&lds[buf][r * 64 + slot * 8]);
    }
    #pragma unroll
    for (int n = 0; n < 2; n++) {
      const int co = wn * 64 + n * 16 + r16;
      const int slot = cslot ^ (co & 7);
      b[n] = *reinterpret_cast<const bf16x8*>(&lds[buf][8192 + co * 64 + slot * 8]);
    }
    if (doStage) stage_A(t + 3);
    __builtin_amdgcn_s_barrier();
    __builtin_amdgcn_s_setprio(1);
    #pragma unroll
    for (int m = 0; m < 4; m++) {
      acc[m][0] = __builtin_amdgcn_mfma_f32_16x16x32_bf16(a[m], b[0], acc[m][0], 0, 0, 0);
      acc[m][1] = __builtin_amdgcn_mfma_f32_16x16x32_bf16(a[m], b[1], acc[m][1], 0, 0, 0);
    }
    __builtin_amdgcn_s_setprio(0);
    __builtin_amdgcn_s_barrier();
    // ---------- phase 1 ----------
    #pragma unroll
    for (int n = 2; n < 4; n++) {
      const int co = wn * 64 + n * 16 + r16;
      const int slot = cslot ^ (co & 7);
      b[n] = *reinterpret_cast<const bf16x8*>(&lds[buf][8192 + co * 64 + slot * 8]);
    }
    if (doStage) stage_B(t + 3);
    __builtin_amdgcn_s_barrier();
    __builtin_amdgcn_s_setprio(1);
    #pragma unroll
    for (int m = 0; m < 4; m++) {
      acc[m][2] = __builtin_amdgcn_mfma_f32_16x16x32_bf16(a[m], b[2], acc[m][2], 0, 0, 0);
      acc[m][3] = __builtin_amdgcn_mfma_f32_16x16x32_bf16(a[m], b[3], acc[m][3], 0, 0, 0);
    }
    __builtin_amdgcn_s_setprio(0);
    if (wcode == 8)      asm volatile("s_waitcnt vmcnt(8)" ::: "memory");
    else if (wcode == 4) asm volatile("s_waitcnt vmcnt(4)" ::: "memory");
    else if (wcode == 0) asm volatile("s_waitcnt vmcnt(0)" ::: "memory");
    __builtin_amdgcn_s_barrier();
  };

  // prologue: 3 stages in flight (12 outstanding loads/wave); buf0 ready
  stage_A(0); stage_B(0); stage_A(1); stage_B(1); stage_A(2); stage_B(2);
  asm volatile("s_waitcnt vmcnt(8)" ::: "memory");
  __builtin_amdgcn_s_barrier();

  for (int t = 0; t < K3_NT - 3; ++t) step(t, true, 8);
  step(K3_NT - 3, false, 4);
  step(K3_NT - 2, false, 0);
  step(K3_NT - 1, false, -1);

  // ---- merge kk pairs: waves 4-7 dump acc to LDS, waves 0-3 add + store ----
  float* red = reinterpret_cast<float*>(&lds[0][0]);   // 64 KB scratch (bufs 0-1)
  if (kk == 1) {
    float* dst = red + wq * 4096;
    #pragma unroll
    for (int m = 0; m < 4; m++)
      #pragma unroll
      for (int n = 0; n < 4; n++)
        *reinterpret_cast<f32x4*>(&dst[(m * 4 + n) * 256 + l * 4]) = acc[m][n];
  }
  __syncthreads();
  if (kk == 0) {
    const float* srcr = red + wq * 4096;
    float* outP = h ? out1 : out0;
    #pragma unroll
    for (int m = 0; m < 4; m++) {
      const int xr = wm * 64 + m * 16 + hi * 4;
      #pragma unroll
      for (int n = 0; n < 4; n++) {
        f32x4 o = *reinterpret_cast<const f32x4*>(&srcr[(m * 4 + n) * 256 + l * 4]);
        f32x4 r = acc[m][n] + o;
        const int co = wn * 64 + n * 16 + r16;
        *reinterpret_cast<f32x4*>(&outP[((size_t)co << 14) + (z << 7) + xr]) = r;
      }
    }
  }
}

// ============ K4: fused split-K reduce + per-channel LN + exact GELU ============
// v2 (FROZEN): 1024 threads/block -> v[4], no VGPR spill.
__device__ __forceinline__ float gelu_exact(float x) {
  return 0.5f * x * (1.0f + erff(x * 0.70710678118654752440f));
}

__global__ __launch_bounds__(1024) void k4_ln(const float* __restrict__ c0,
                                              const float* __restrict__ c1,
                                              float* __restrict__ outp) {
  const int co = blockIdx.x;
  const int t = threadIdx.x;
  const float4* p0 = reinterpret_cast<const float4*>(c0 + ((size_t)co << 14));
  const float4* p1 = reinterpret_cast<const float4*>(c1 + ((size_t)co << 14));
  float4 v[4];
  float s = 0.f, s2 = 0.f;
  #pragma unroll
  for (int i = 0; i < 4; i++) {
    float4 a = p0[t + (i << 10)];
    float4 b = p1[t + (i << 10)];
    float4 r;
    r.x = a.x + b.x; r.y = a.y + b.y; r.z = a.z + b.z; r.w = a.w + b.w;
    v[i] = r;
    s  += r.x + r.y + r.z + r.w;
    s2 += r.x * r.x + r.y * r.y + r.z * r.z + r.w * r.w;
  }
  #pragma unroll
  for (int off = 32; off > 0; off >>= 1) {
    s  += __shfl_down(s, off);
    s2 += __shfl_down(s2, off);
  }
  __shared__ float red[32];
  __shared__ float mb[2];
  const int wv = t >> 6, ln = t & 63;
  if (ln == 0) { red[wv] = s; red[wv + 16] = s2; }
  __syncthreads();
  if (t == 0) {
    float S = 0.f, S2 = 0.f;
    #pragma unroll
    for (int i = 0; i < 16; i++) { S += red[i]; S2 += red[i + 16]; }
    float mu = S * (1.0f / 16384.0f);
    float var = S2 * (1.0f / 16384.0f) - mu * mu;
    mb[0] = mu;
    mb[1] = 1.0f / sqrtf(var + 1e-5f);
  }
  __syncthreads();
  const float mu = mb[0], inv = mb[1];
  float4* op = reinterpret_cast<float4*>(outp + ((size_t)co << 14));
  #pragma unroll
  for (int i = 0; i < 4; i++) {
    float4 x = v[i];
    float4 r;
    r.x = gelu_exact((x.x - mu) * inv);
    r.y = gelu_exact((x.y - mu) * inv);
    r.z = gelu_exact((x.z - mu) * inv);
    r.w = gelu_exact((x.w - mu) * inv);
    op[t + (i << 10)] = r;
  }
}

extern "C" void kernel_launch(void* const* d_in, const int* in_sizes, int n_in,
                              void* d_out, int out_size, void* d_ws, size_t ws_size,
                              hipStream_t stream) {
  const float* cam_feat = (const float*)d_in[0];
  const float* cam2ego  = (const float*)d_in[1];
  const float* intr     = (const float*)d_in[2];
  const float* conv_w   = (const float*)d_in[3];
  float* out = (float*)d_out;
  char* ws = (char*)d_ws;

  float*          P     = (float*)(ws + OFF_P);
  __hip_bfloat16* Wp    = (__hip_bfloat16*)(ws + OFF_W);
  unsigned*       camT2 = (unsigned*)(ws + OFF_CAMT);
  __hip_bfloat16* F     = (__hip_bfloat16*)(ws + OFF_F);
  float*          conv0 = (float*)(ws + OFF_CONV);
  float*          conv1 = (float*)(ws + OFF_CAMT);  // camT2 slot is dead after k2

  hipLaunchKernelGGL(k_pre, dim3(705), dim3(256), 0, stream,
                     cam_feat, conv_w, cam2ego, intr, camT2, Wp, P);
  hipLaunchKernelGGL(k2_sample, dim3(4225), dim3(256), 0, stream, camT2, P, F);
  hipLaunchKernelGGL(k3_gemm, dim3(256), dim3(512), 0, stream, F, Wp, conv0, conv1);
  hipLaunchKernelGGL(k4_ln, dim3(128), dim3(1024), 0, stream, conv0, conv1, out);
}